// Round 9
// baseline (125.627 us; speedup 1.0000x reference)
//
#include <hip/hip_runtime.h>
#include <math.h>

#define Ec 256
#define Sc 512
#define Bc 2
#define Hc 8
#define Dc 32
#define MAXNORM (1.0f - 1e-5f)
#define NEc (Bc * Sc * Ec)
#define KSPLIT 2
#define NROWS (Bc * Hc * Sc)   // 8192 (b,h,s) rows

__device__ __forceinline__ float fullWaveSum(float v) {
#pragma unroll
  for (int m = 32; m >= 1; m >>= 1) v += __shfl_xor(v, m, 64);
  return v;
}
__device__ __forceinline__ float halfWaveSum(float v) {
#pragma unroll
  for (int m = 16; m >= 1; m >>= 1) v += __shfl_xor(v, m, 64);
  return v;
}
__device__ __forceinline__ float atanh_fast(float z) {   // z in [0, 1)
  return 0.5f * __logf((1.0f + z) / (1.0f - z));
}
__device__ __forceinline__ float tanh_fast(float a) {    // a >= 0
  float e = __expf(-2.0f * a);
  return (1.0f - e) / (1.0f + e);
}

// ---------------------------------------------------------------------------
// Tiled GEMM partial: O[kz] = X[:, kz*128:(kz+1)*128] @ W[:, same]^T
// Tile 32 rows x 64 cols, K-chunks of 64. grid (M/32, 4*nmat, 2), blk 128.
// ---------------------------------------------------------------------------
__global__ __launch_bounds__(128) void gemm_xwt(
    const float* __restrict__ X,
    const float* __restrict__ W0, const float* __restrict__ W1,
    const float* __restrict__ W2,
    float* __restrict__ O0, float* __restrict__ O1, float* __restrict__ O2) {
  const int tid = threadIdx.x;
  const int bx = blockIdx.x;
  const int by = blockIdx.y;
  const int kz = blockIdx.z;
  const int mat = by >> 2;
  const int cb0 = (by & 3) * 64;
  const int rb0 = bx * 32;
  const float* __restrict__ W = (mat == 0) ? W0 : (mat == 1) ? W1 : W2;
  float* __restrict__ O = ((mat == 0) ? O0 : (mat == 1) ? O1 : O2) + (size_t)kz * NEc;

  __shared__ float Xs[64][36];   // [k][row]
  __shared__ float Ws[64][68];   // [k][col]

  const int f4 = tid & 15;
  const int sub = tid >> 4;
  const int ty = tid >> 4;
  const int tx = tid & 15;

  float acc[4][4];
#pragma unroll
  for (int i = 0; i < 4; ++i)
#pragma unroll
    for (int j = 0; j < 4; ++j) acc[i][j] = 0.f;

  for (int kk = kz * 128; kk < kz * 128 + 128; kk += 64) {
    __syncthreads();
#pragma unroll
    for (int i = 0; i < 4; ++i) {
      int row = sub + i * 8;
      float4 v = *(const float4*)&X[(size_t)(rb0 + row) * Ec + kk + f4 * 4];
      Xs[f4 * 4 + 0][row] = v.x;
      Xs[f4 * 4 + 1][row] = v.y;
      Xs[f4 * 4 + 2][row] = v.z;
      Xs[f4 * 4 + 3][row] = v.w;
    }
#pragma unroll
    for (int i = 0; i < 8; ++i) {
      int col = sub + i * 8;
      float4 v = *(const float4*)&W[(size_t)(cb0 + col) * Ec + kk + f4 * 4];
      Ws[f4 * 4 + 0][col] = v.x;
      Ws[f4 * 4 + 1][col] = v.y;
      Ws[f4 * 4 + 2][col] = v.z;
      Ws[f4 * 4 + 3][col] = v.w;
    }
    __syncthreads();
#pragma unroll 8
    for (int k = 0; k < 64; ++k) {
      float4 a = *(const float4*)&Xs[k][ty * 4];
      float4 b = *(const float4*)&Ws[k][tx * 4];
      float av[4] = {a.x, a.y, a.z, a.w};
      float bv[4] = {b.x, b.y, b.z, b.w};
#pragma unroll
      for (int i = 0; i < 4; ++i)
#pragma unroll
        for (int j = 0; j < 4; ++j) acc[i][j] = fmaf(av[i], bv[j], acc[i][j]);
    }
  }
#pragma unroll
  for (int i = 0; i < 4; ++i) {
    float4 o = make_float4(acc[i][0], acc[i][1], acc[i][2], acc[i][3]);
    *(float4*)&O[(size_t)(rb0 + ty * 4 + i) * Ec + cb0 + tx * 4] = o;
  }
}

// ---------------------------------------------------------------------------
// Per-row hyp_linear epilogue for q/k/v (sums the 2 K-split partials)
// ---------------------------------------------------------------------------
__global__ __launch_bounds__(256) void qkv_stats(
    const float* __restrict__ x,
    const float* __restrict__ mxq, const float* __restrict__ mxk,
    const float* __restrict__ mxv,
    const float* __restrict__ bq, const float* __restrict__ bk,
    const float* __restrict__ bv,
    float* __restrict__ qo, float* __restrict__ ko, float* __restrict__ lvo,
    float* __restrict__ qno, float* __restrict__ kno) {
  const int t = threadIdx.x;
  const int row = blockIdx.x;
  const int b = row >> 9;
  const int s = row & (Sc - 1);
  const size_t idx = (size_t)row * Ec + t;
  const float xv = x[idx];
  float mq = 0.f, mk = 0.f, mv = 0.f;
#pragma unroll
  for (int p = 0; p < KSPLIT; ++p) {
    mq += mxq[idx + (size_t)p * NEc];
    mk += mxk[idx + (size_t)p * NEc];
    mv += mxv[idx + (size_t)p * NEc];
  }
  const float bb[3] = {bq[t], bk[t], bv[t]};
  const float mvals[3] = {mq, mk, mv};

  float vals[10] = {xv * xv,
                    mq * mq, mq * bb[0], bb[0] * bb[0],
                    mk * mk, mk * bb[1], bb[1] * bb[1],
                    mv * mv, mv * bb[2], bb[2] * bb[2]};
  __shared__ float red[10][4];
  __shared__ float fin[10];
#pragma unroll
  for (int i = 0; i < 10; ++i) {
    float v = fullWaveSum(vals[i]);
    if ((t & 63) == 0) red[i][t >> 6] = v;
  }
  __syncthreads();
  if (t < 10) fin[t] = red[t][0] + red[t][1] + red[t][2] + red[t][3];
  __syncthreads();

  const float x2 = fin[0];
  const float xn = sqrtf(fmaxf(x2, 1e-15f));
  const float at = atanh_fast(fminf(xn, MAXNORM));  // SC = 1
  const int h = t >> 5;

#pragma unroll
  for (int m = 0; m < 3; ++m) {
    float mx2 = fin[1 + 3 * m];
    float mxb = fin[2 + 3 * m];
    float b2 = fin[3 + 3 * m];
    float mxn = sqrtf(fmaxf(mx2, 1e-15f));
    float scl = tanh_fast((mxn / xn) * at) / mxn;
    float mvv = scl * mvals[m];
    float X2 = scl * scl * mx2;
    float XY = scl * mxb;
    float numc = 1.0f + 2.0f * XY + b2;
    float den = 1.0f + 2.0f * XY + X2 * b2 + 1e-15f;
    float res = (numc * mvv + (1.0f - X2) * bb[m]) / den;
    if (m < 2) {
      res = fminf(res, MAXNORM);                 // elementwise clamp_max
      float s2 = halfWaveSum(res * res);         // per-head ||.||^2 (C=1)
      if (m == 0) {
        qo[idx] = res;
        if ((t & 31) == 0) qno[(b * Hc + h) * Sc + s] = s2;
      } else {
        ko[idx] = res;
        if ((t & 31) == 0) kno[(b * Hc + h) * Sc + s] = s2;
      }
    } else {
      float vn2 = halfWaveSum(res * res);
      float vn = sqrtf(fmaxf(vn2, 1e-15f));
      float f = atanh_fast(fminf(vn, MAXNORM)) / vn;  // logmap0 factor
      lvo[idx] = f * res;
    }
  }
}

// ---------------------------------------------------------------------------
// Fused attention: scores (Gram GEMM + hyperbolic transform) and P@LV in one
// kernel; P-tile lives only in LDS (no HBM round-trip).
// grid (16 q-tiles of 32, 16 bh) = 256 blocks (1/CU), block 512 (2 waves/SIMD)
// Phase A ids: ty=tid>>6 (8 groups of 4 q-rows), tx=tid&63 (64 groups of 4 k)
//   -> 4x4 register tile, 2 B/FMA LDS ratio (XOR-swizzled Qs/Ks).
// Phase B ids: js=tid>>6 (8 j-slices of 32), rg=(tid>>3)&7, dq=tid&7
//   -> pv-v2 mapping: 4 rows x 4 dims per thread, 2 B/FMA. 8-way js merge.
// ---------------------------------------------------------------------------
__global__ __launch_bounds__(512) void attn_fused(
    const float* __restrict__ q, const float* __restrict__ k,
    const float* __restrict__ lv, const float* __restrict__ qn,
    const float* __restrict__ kn, const float* __restrict__ hs,
    float* __restrict__ out) {
  const int tid = threadIdx.x;
  const int qt = blockIdx.x;
  const int bh = blockIdx.y;
  const int b = bh >> 3;
  const int h = bh & 7;
  const int sq0 = qt * 32;

  __shared__ float Qs[32][32];      // swizzled
  __shared__ float Ks[256][32];     // swizzled
  __shared__ float lvs[256][36];
  __shared__ float Ps[32][260];
  __shared__ float accm[32][8][32];
  __shared__ float lsb[32][8];

  const int ty = tid >> 6;          // phase A: 4 q-rows
  const int tx = tid & 63;          // phase A: 4 k-cols
  const int js = tid >> 6;          // phase B: j-slice
  const int rg = (tid >> 3) & 7;    // phase B: row-quad
  const int dq = tid & 7;           // phase B: dim-quad

  // stage Q once (32 rows x 8 f4)
  if (tid < 256) {
    int r = tid >> 3, fd = tid & 7;
    int fsw = fd ^ ((r >> 2) & 7);
    *(float4*)&Qs[r][fsw * 4] =
        *(const float4*)&q[(size_t)(b * Sc + sq0 + r) * Ec + h * Dc + fd * 4];
  }
  const float sinv = -1.0f / (hs[h] * sqrtf((float)Dc));
  float qnv[4];
#pragma unroll
  for (int i = 0; i < 4; ++i) qnv[i] = qn[bh * Sc + sq0 + ty * 4 + i];

  float4 oacc[4];
#pragma unroll
  for (int i = 0; i < 4; ++i) oacc[i] = make_float4(0.f, 0.f, 0.f, 0.f);
  float lsum4[4] = {0.f, 0.f, 0.f, 0.f};

#pragma unroll 1
  for (int kt = 0; kt < 2; ++kt) {
    const int k0 = kt * 256;
    __syncthreads();   // protect prior-iter reads of Ks/lvs/Ps
#pragma unroll
    for (int i = 0; i < 4; ++i) {
      int qi = tid + i * 512;
      int r = qi >> 3, fd = qi & 7;
      int fsw = fd ^ ((r >> 2) & 7);
      *(float4*)&Ks[r][fsw * 4] =
          *(const float4*)&k[(size_t)(b * Sc + k0 + r) * Ec + h * Dc + fd * 4];
      *(float4*)&lvs[r][fd * 4] =
          *(const float4*)&lv[(size_t)(b * Sc + k0 + r) * Ec + h * Dc + fd * 4];
    }
    float knv[4];
#pragma unroll
    for (int j = 0; j < 4; ++j) knv[j] = kn[bh * Sc + k0 + tx * 4 + j];
    __syncthreads();

    // ---- phase A: 4x4 Gram dots ----
    float acc[4][4];
#pragma unroll
    for (int i = 0; i < 4; ++i)
#pragma unroll
      for (int j = 0; j < 4; ++j) acc[i][j] = 0.f;
#pragma unroll
    for (int fd = 0; fd < 8; ++fd) {
      const int qsw = (fd ^ (ty & 7)) * 4;
      const int ksw = (fd ^ (tx & 7)) * 4;
      float4 a[4], bb[4];
#pragma unroll
      for (int i = 0; i < 4; ++i) a[i] = *(const float4*)&Qs[ty * 4 + i][qsw];
#pragma unroll
      for (int j = 0; j < 4; ++j) bb[j] = *(const float4*)&Ks[tx * 4 + j][ksw];
#pragma unroll
      for (int i = 0; i < 4; ++i)
#pragma unroll
        for (int j = 0; j < 4; ++j) {
          acc[i][j] = fmaf(a[i].x, bb[j].x, acc[i][j]);
          acc[i][j] = fmaf(a[i].y, bb[j].y, acc[i][j]);
          acc[i][j] = fmaf(a[i].z, bb[j].z, acc[i][j]);
          acc[i][j] = fmaf(a[i].w, bb[j].w, acc[i][j]);
        }
    }
    // score transform -> Ps
#pragma unroll
    for (int i = 0; i < 4; ++i) {
      const float q2 = qnv[i];
      const float omq = 1.0f - q2;
      float po[4];
#pragma unroll
      for (int j = 0; j < 4; ++j) {
        const float k2 = knv[j];
        const float kq = acc[i][j];
        const float omk = 1.0f - k2;
        float s2x2 = fmaf(-4.0f, kq, 2.0f * k2 + 2.0f * q2);     // 2||q-k||^2
        float dden = fmaf(k2, q2, fmaf(-2.0f, kq, 1.0f)) + 1e-15f;
        float Pd = fmaf(dden, omk * omq, 1e-20f);
        float rp = __builtin_amdgcn_rcpf(Pd);
        float tt = fmaxf(s2x2 * rp, 1e-7f);                      // a-1
        float z = (1.0f + tt) + sqrtf(fmaf(tt, tt, tt + tt));
        po[j] = __builtin_amdgcn_exp2f(sinv * __builtin_amdgcn_logf(z));
      }
      float4 o4 = make_float4(po[0], po[1], po[2], po[3]);
      *(float4*)&Ps[ty * 4 + i][tx * 4] = o4;
    }
    __syncthreads();

    // ---- phase B: P-tile @ LV-tile ----
#pragma unroll
    for (int jq = 0; jq < 8; ++jq) {
      const int j0 = js * 32 + jq * 4;
      float4 p[4], l[4];
#pragma unroll
      for (int i = 0; i < 4; ++i) p[i] = *(const float4*)&Ps[rg * 4 + i][j0];
#pragma unroll
      for (int c = 0; c < 4; ++c) l[c] = *(const float4*)&lvs[j0 + c][dq * 4];
#pragma unroll
      for (int i = 0; i < 4; ++i) {
        lsum4[i] += (p[i].x + p[i].y) + (p[i].z + p[i].w);
        oacc[i].x = fmaf(p[i].x, l[0].x, oacc[i].x);
        oacc[i].y = fmaf(p[i].x, l[0].y, oacc[i].y);
        oacc[i].z = fmaf(p[i].x, l[0].z, oacc[i].z);
        oacc[i].w = fmaf(p[i].x, l[0].w, oacc[i].w);
        oacc[i].x = fmaf(p[i].y, l[1].x, oacc[i].x);
        oacc[i].y = fmaf(p[i].y, l[1].y, oacc[i].y);
        oacc[i].z = fmaf(p[i].y, l[1].z, oacc[i].z);
        oacc[i].w = fmaf(p[i].y, l[1].w, oacc[i].w);
        oacc[i].x = fmaf(p[i].z, l[2].x, oacc[i].x);
        oacc[i].y = fmaf(p[i].z, l[2].y, oacc[i].y);
        oacc[i].z = fmaf(p[i].z, l[2].z, oacc[i].z);
        oacc[i].w = fmaf(p[i].z, l[2].w, oacc[i].w);
        oacc[i].x = fmaf(p[i].w, l[3].x, oacc[i].x);
        oacc[i].y = fmaf(p[i].w, l[3].y, oacc[i].y);
        oacc[i].z = fmaf(p[i].w, l[3].z, oacc[i].z);
        oacc[i].w = fmaf(p[i].w, l[3].w, oacc[i].w);
      }
    }
  }

  // ---- merge js partials + expmap0 epilogue ----
  __syncthreads();
#pragma unroll
  for (int i = 0; i < 4; ++i)
    *(float4*)&accm[rg * 4 + i][js][dq * 4] = oacc[i];
  if (dq == 0) {
#pragma unroll
    for (int i = 0; i < 4; ++i) lsb[rg * 4 + i][js] = lsum4[i];
  }
  __syncthreads();

  if (tid < 256) {
    const int rw = tid >> 3;     // 0..31
    const int d2 = tid & 7;      // dim-quad
    float4 o = make_float4(0.f, 0.f, 0.f, 0.f);
    float ls = 0.f;
#pragma unroll
    for (int g = 0; g < 8; ++g) {
      float4 a4 = *(const float4*)&accm[rw][g][d2 * 4];
      o.x += a4.x; o.y += a4.y; o.z += a4.z; o.w += a4.w;
      ls += lsb[rw][g];
    }
    const float li = 1.0f / ls;
    o.x *= li; o.y *= li; o.z *= li; o.w *= li;
    float un2 = fmaf(o.x, o.x, fmaf(o.y, o.y, fmaf(o.z, o.z, o.w * o.w)));
#pragma unroll
    for (int m = 4; m >= 1; m >>= 1) un2 += __shfl_xor(un2, m, 8);
    float un = sqrtf(fmaxf(un2, 1e-15f));
    float f = tanh_fast(un) / un;      // expmap0 factor (SC = 1)
    float4 ov = make_float4(o.x * f, o.y * f, o.z * f, o.w * f);
    *(float4*)&out[(size_t)(b * Sc + sq0 + rw) * Ec + h * Dc + d2 * 4] = ov;
  }
}

// ---------------------------------------------------------------------------
// Per-row hyp_linear epilogue for the output projection (sums K-split partials)
// ---------------------------------------------------------------------------
__global__ __launch_bounds__(256) void proj_stats(
    const float* __restrict__ xin, const float* __restrict__ mx,
    const float* __restrict__ bo, float* __restrict__ out) {
  const int t = threadIdx.x;
  const int row = blockIdx.x;
  const size_t idx = (size_t)row * Ec + t;
  const float xv = xin[idx];
  float m = 0.f;
#pragma unroll
  for (int p = 0; p < KSPLIT; ++p) m += mx[idx + (size_t)p * NEc];
  const float bb = bo[t];
  float vals[4] = {xv * xv, m * m, m * bb, bb * bb};
  __shared__ float red[4][4];
  __shared__ float fin[4];
#pragma unroll
  for (int i = 0; i < 4; ++i) {
    float v = fullWaveSum(vals[i]);
    if ((t & 63) == 0) red[i][t >> 6] = v;
  }
  __syncthreads();
  if (t < 4) fin[t] = red[t][0] + red[t][1] + red[t][2] + red[t][3];
  __syncthreads();

  float x2 = fin[0], mx2 = fin[1], mxb = fin[2], b2 = fin[3];
  float xn = sqrtf(fmaxf(x2, 1e-15f));
  float mxn = sqrtf(fmaxf(mx2, 1e-15f));
  float scl = tanh_fast((mxn / xn) * atanh_fast(fminf(xn, MAXNORM))) / mxn;
  float mvv = scl * m;
  float X2 = scl * scl * mx2;
  float XY = scl * mxb;
  float numc = 1.0f + 2.0f * XY + b2;
  float den = 1.0f + 2.0f * XY + X2 * b2 + 1e-15f;
  out[idx] = (numc * mvv + (1.0f - X2) * bb) / den;
}

extern "C" void kernel_launch(void* const* d_in, const int* in_sizes, int n_in,
                              void* d_out, int out_size, void* d_ws, size_t ws_size,
                              hipStream_t stream) {
  (void)in_sizes; (void)n_in; (void)out_size; (void)ws_size;
  const float* x  = (const float*)d_in[0];
  const float* Wq = (const float*)d_in[1];
  const float* bq = (const float*)d_in[2];
  const float* Wk = (const float*)d_in[3];
  const float* bk = (const float*)d_in[4];
  const float* Wv = (const float*)d_in[5];
  const float* bv = (const float*)d_in[6];
  const float* Wo = (const float*)d_in[7];
  const float* bo = (const float*)d_in[8];
  const float* hs = (const float*)d_in[9];

  float* ws = (float*)d_ws;
  const int NE = NEc;            // 262144
  const int NH = NROWS;          // 8192
  float* mxq = ws;               // KSPLIT*NE partials each
  float* mxk = mxq + KSPLIT * NE;
  float* mxv = mxk + KSPLIT * NE;
  float* mxo = mxv + KSPLIT * NE;
  float* qb  = mxo + KSPLIT * NE;
  float* kb  = qb + NE;
  float* lvb = kb + NE;
  float* aob = lvb + NE;
  float* qnb = aob + NE;
  float* knb = qnb + NH;

  const int M = Bc * Sc;  // 1024 rows

  gemm_xwt<<<dim3(M / 32, 12, KSPLIT), 128, 0, stream>>>(x, Wq, Wk, Wv, mxq, mxk, mxv);
  qkv_stats<<<M, 256, 0, stream>>>(x, mxq, mxk, mxv, bq, bk, bv,
                                   qb, kb, lvb, qnb, knb);
  attn_fused<<<dim3(16, 16), 512, 0, stream>>>(qb, kb, lvb, qnb, knb, hs, aob);
  gemm_xwt<<<dim3(M / 32, 4, KSPLIT), 128, 0, stream>>>(aob, Wo, Wo, Wo, mxo, mxo, mxo);
  proj_stats<<<M, 256, 0, stream>>>(aob, mxo, bo, (float*)d_out);
}